// Round 2
// baseline (58.135 us; speedup 1.0000x reference)
//
#include <hip/hip_runtime.h>
#include <stdint.h>

// ---------------------------------------------------------------------------
// FractalLinear: IFS chaos game (JAX threefry-exact) + bilinear gather/scatter
// ---------------------------------------------------------------------------
// PRNG mode: 1 = jax_threefry_partitionable (default True since jax 0.4.36),
//            0 = legacy split-half counter mode. Flip if absmax ~1e6.
#ifndef PRNG_PARTITIONABLE
#define PRNG_PARTITIONABLE 1
#endif

namespace {

constexpr int kH  = 8192;
constexpr int kW  = 16384;
constexpr int kNT = 8;
constexpr int kNP = 1000;
constexpr int kCI = 10;

__device__ __forceinline__ uint32_t rotl32(uint32_t x, int n) {
  return (x << n) | (x >> (32 - n));
}

// Threefry-2x32, 20 rounds (Random123 / JAX convention).
__device__ void threefry2x32(uint32_t k0, uint32_t k1, uint32_t c0, uint32_t c1,
                             uint32_t& o0, uint32_t& o1) {
  const uint32_t ks2 = k0 ^ k1 ^ 0x1BD11BDAu;
  uint32_t x0 = c0 + k0, x1 = c1 + k1;
#define TF_R(r) { x0 += x1; x1 = rotl32(x1, (r)); x1 ^= x0; }
  TF_R(13) TF_R(15) TF_R(26) TF_R(6)
  x0 += k1;  x1 += ks2 + 1u;
  TF_R(17) TF_R(29) TF_R(16) TF_R(24)
  x0 += ks2; x1 += k0 + 2u;
  TF_R(13) TF_R(15) TF_R(26) TF_R(6)
  x0 += k0;  x1 += k1 + 3u;
  TF_R(17) TF_R(29) TF_R(16) TF_R(24)
  x0 += k1;  x1 += ks2 + 4u;
  TF_R(13) TF_R(15) TF_R(26) TF_R(6)
  x0 += ks2; x1 += k0 + 5u;
#undef TF_R
  o0 = x0; o1 = x1;
}

// 32-bit random bits, flat index i, for an array of `size` elements.
__device__ __forceinline__ uint32_t random_bits32(uint32_t k0, uint32_t k1,
                                                  uint32_t i, uint32_t size) {
#if PRNG_PARTITIONABLE
  // counts = 64-bit linear iota; bits = o0 ^ o1
  uint32_t o0, o1;
  threefry2x32(k0, k1, 0u /* hi(i) */, i, o0, o1);
  (void)size;
  return o0 ^ o1;
#else
  // legacy: counts = iota(size) split in half; even size assumed here
  const uint32_t half = size / 2u;
  const uint32_t j = (i < half) ? i : (i - half);
  uint32_t o0, o1;
  threefry2x32(k0, k1, j, j + half, o0, o1);
  return (i < half) ? o0 : o1;
#endif
}

__device__ __forceinline__ float u01(uint32_t bits) {
  return __uint_as_float((bits >> 9) | 0x3f800000u) - 1.0f;
}

// x86 cvttss2si semantics: out-of-range / NaN -> INT_MIN (matches CPU-ref).
__device__ __forceinline__ int cvt_f32_i32_x86(float v) {
  if (!(v >= -2147483648.0f && v < 2147483648.0f)) return (int)0x80000000;
  return (int)v;
}

// ---------------------------------------------------------------------------
// Kernel 1: run the chaos game, emit per-point {x_low, x_w, y_low, y_w}.
// ---------------------------------------------------------------------------
__global__ __launch_bounds__(256) void fractal_chaos(
    const float* __restrict__ dna, int4* __restrict__ rec) {
  const int n = blockIdx.x * blockDim.x + threadIdx.x;
  if (n >= kNP) return;

  // base key = jax.random.key(1) -> (0, 1); kp, kg = split(key, 2)
  uint32_t kp0, kp1, kg0, kg1;
#if PRNG_PARTITIONABLE
  threefry2x32(0u, 1u, 0u, 0u, kp0, kp1);   // fold_in(key, 0)
  threefry2x32(0u, 1u, 0u, 1u, kg0, kg1);   // fold_in(key, 1)
#else
  uint32_t a0, a1, b0, b1;
  threefry2x32(0u, 1u, 0u, 2u, a0, a1);
  threefry2x32(0u, 1u, 1u, 3u, b0, b1);
  kp0 = a0; kp1 = b0; kg0 = a1; kg1 = b1;
#endif

  // initial points: uniform(kp, (1000,2)) * 2 - 1
  const uint32_t bx = random_bits32(kp0, kp1, (uint32_t)(2 * n),     2u * kNP);
  const uint32_t by = random_bits32(kp0, kp1, (uint32_t)(2 * n + 1), 2u * kNP);
  float px = u01(bx) * 2.0f - 1.0f;
  float py = u01(by) * 2.0f - 1.0f;

  for (int i = 0; i < kCI; ++i) {
    // ki = fold_in(kg, i)
    uint32_t ki0, ki1;
    threefry2x32(kg0, kg1, 0u, (uint32_t)i, ki0, ki1);

    float best = -INFINITY;
    int bt = 0;
    #pragma unroll
    for (int t = 0; t < kNT; ++t) {
      const uint32_t bb = random_bits32(ki0, ki1, (uint32_t)(n * kNT + t),
                                        (uint32_t)(kNP * kNT));
      float u = fmaxf(u01(bb), 1.17549435e-38f);     // minval = f32 tiny
      const float g = -logf(-logf(u));               // gumbel
      const float z = dna[t * 7 + 6] + g;            // logits + g
      if (z > best) { best = z; bt = t; }            // first-max like argmax
    }
    const float A = dna[bt * 7 + 0], Bb = dna[bt * 7 + 1];
    const float C = dna[bt * 7 + 2], D  = dna[bt * 7 + 3];
    const float E = dna[bt * 7 + 4], F  = dna[bt * 7 + 5];
    const float nx = A * px + Bb * py + E;
    const float ny = C * px + D  * py + F;
    px = nx; py = ny;
  }

  const float xc = ((px + 1.0f) * 0.5f) * (float)(kW - 1);
  const float yc = ((py + 1.0f) * 0.5f) * (float)(kH - 1);
  int xl = cvt_f32_i32_x86(floorf(xc));
  int yl = cvt_f32_i32_x86(floorf(yc));
  xl = min(max(xl, 0), kW - 2);
  yl = min(max(yl, 0), kH - 2);
  const float xw = xc - (float)xl;   // NOT clipped (matches reference)
  const float yw = yc - (float)yl;

  rec[n] = make_int4(xl, __float_as_int(xw), yl, __float_as_int(yw));
}

// ---------------------------------------------------------------------------
// Kernel 2: per batch row, bilinear gather from x, scatter-add into LDS
// accumulator over H, then out = acc/1000 + bias.
// ---------------------------------------------------------------------------
__global__ __launch_bounds__(256) void fractal_apply(
    const float* __restrict__ x, const float* __restrict__ bias,
    const int4* __restrict__ rec, float* __restrict__ out) {
  __shared__ float acc[kH];
  const int b = blockIdx.x;

  float4* acc4 = reinterpret_cast<float4*>(acc);
  for (int i = threadIdx.x; i < kH / 4; i += 256)
    acc4[i] = make_float4(0.f, 0.f, 0.f, 0.f);
  __syncthreads();

  const float* __restrict__ xrow = x + (size_t)b * kW;
  for (int n = threadIdx.x; n < kNP; n += 256) {
    const int4 r = rec[n];
    const int xl = r.x;
    const float xw = __int_as_float(r.y);
    const int yl = r.z;
    const float yw = __int_as_float(r.w);
    const float xv = xrow[xl] * (1.0f - xw) + xrow[xl + 1] * xw;
    atomicAdd(&acc[yl],     xv * (1.0f - yw));
    atomicAdd(&acc[yl + 1], xv * yw);
  }
  __syncthreads();

  const float4* __restrict__ bias4 = reinterpret_cast<const float4*>(bias);
  float4* __restrict__ out4 = reinterpret_cast<float4*>(out + (size_t)b * kH);
  for (int i = threadIdx.x; i < kH / 4; i += 256) {
    const float4 a  = acc4[i];
    const float4 bi = bias4[i];
    float4 o;
    o.x = a.x / 1000.0f + bi.x;
    o.y = a.y / 1000.0f + bi.y;
    o.z = a.z / 1000.0f + bi.z;
    o.w = a.w / 1000.0f + bi.w;
    out4[i] = o;
  }
}

}  // namespace

extern "C" void kernel_launch(void* const* d_in, const int* in_sizes, int n_in,
                              void* d_out, int out_size, void* d_ws, size_t ws_size,
                              hipStream_t stream) {
  const float* x    = (const float*)d_in[0];   // (2048, 16384)
  const float* dna  = (const float*)d_in[1];   // (56,)
  const float* bias = (const float*)d_in[2];   // (8192,)
  float* out = (float*)d_out;                  // (2048, 8192)
  int4* rec = (int4*)d_ws;                     // 1000 * 16B scratch

  fractal_chaos<<<(kNP + 255) / 256, 256, 0, stream>>>(dna, rec);

  const int B = in_sizes[0] / kW;              // 2048
  fractal_apply<<<B, 256, 0, stream>>>(x, bias, rec, out);
}

// Round 3
// 57.875 us; speedup vs baseline: 1.0045x; 1.0045x over previous
//
#include <hip/hip_runtime.h>
#include <stdint.h>

// ---------------------------------------------------------------------------
// FractalLinear: IFS chaos game (JAX threefry-exact) + bilinear gather/scatter
// ---------------------------------------------------------------------------
// PRNG mode: 1 = jax_threefry_partitionable (default True since jax 0.4.36),
//            0 = legacy split-half counter mode. Flip if absmax ~1e6.
#ifndef PRNG_PARTITIONABLE
#define PRNG_PARTITIONABLE 1
#endif

namespace {

constexpr int kH  = 8192;
constexpr int kW  = 16384;
constexpr int kNT = 8;
constexpr int kNP = 1000;
constexpr int kCI = 10;

__device__ __forceinline__ uint32_t rotl32(uint32_t x, int n) {
  return (x << n) | (x >> (32 - n));
}

// Threefry-2x32, 20 rounds (Random123 / JAX convention).
__device__ void threefry2x32(uint32_t k0, uint32_t k1, uint32_t c0, uint32_t c1,
                             uint32_t& o0, uint32_t& o1) {
  const uint32_t ks2 = k0 ^ k1 ^ 0x1BD11BDAu;
  uint32_t x0 = c0 + k0, x1 = c1 + k1;
#define TF_R(r) { x0 += x1; x1 = rotl32(x1, (r)); x1 ^= x0; }
  TF_R(13) TF_R(15) TF_R(26) TF_R(6)
  x0 += k1;  x1 += ks2 + 1u;
  TF_R(17) TF_R(29) TF_R(16) TF_R(24)
  x0 += ks2; x1 += k0 + 2u;
  TF_R(13) TF_R(15) TF_R(26) TF_R(6)
  x0 += k0;  x1 += k1 + 3u;
  TF_R(17) TF_R(29) TF_R(16) TF_R(24)
  x0 += k1;  x1 += ks2 + 4u;
  TF_R(13) TF_R(15) TF_R(26) TF_R(6)
  x0 += ks2; x1 += k0 + 5u;
#undef TF_R
  o0 = x0; o1 = x1;
}

// 32-bit random bits, flat index i, for an array of `size` elements.
__device__ __forceinline__ uint32_t random_bits32(uint32_t k0, uint32_t k1,
                                                  uint32_t i, uint32_t size) {
#if PRNG_PARTITIONABLE
  // counts = 64-bit linear iota; bits = o0 ^ o1
  uint32_t o0, o1;
  threefry2x32(k0, k1, 0u /* hi(i) */, i, o0, o1);
  (void)size;
  return o0 ^ o1;
#else
  // legacy: counts = iota(size) split in half; even size assumed here
  const uint32_t half = size / 2u;
  const uint32_t j = (i < half) ? i : (i - half);
  uint32_t o0, o1;
  threefry2x32(k0, k1, j, j + half, o0, o1);
  return (i < half) ? o0 : o1;
#endif
}

__device__ __forceinline__ float u01(uint32_t bits) {
  return __uint_as_float((bits >> 9) | 0x3f800000u) - 1.0f;
}

// x86 cvttss2si semantics: out-of-range / NaN -> INT_MIN (matches CPU-ref).
__device__ __forceinline__ int cvt_f32_i32_x86(float v) {
  if (!(v >= -2147483648.0f && v < 2147483648.0f)) return (int)0x80000000;
  return (int)v;
}

// ---------------------------------------------------------------------------
// Kernel 1: run the chaos game, emit per-point {x_low, x_w, y_low, y_w}.
// ---------------------------------------------------------------------------
__global__ __launch_bounds__(256) void fractal_chaos(
    const float* __restrict__ dna, int4* __restrict__ rec) {
  const int n = blockIdx.x * blockDim.x + threadIdx.x;
  if (n >= kNP) return;

  // base key = jax.random.key(1) -> (0, 1); kp, kg = split(key, 2)
  uint32_t kp0, kp1, kg0, kg1;
#if PRNG_PARTITIONABLE
  threefry2x32(0u, 1u, 0u, 0u, kp0, kp1);   // fold_in(key, 0)
  threefry2x32(0u, 1u, 0u, 1u, kg0, kg1);   // fold_in(key, 1)
#else
  uint32_t a0, a1, b0, b1;
  threefry2x32(0u, 1u, 0u, 2u, a0, a1);
  threefry2x32(0u, 1u, 1u, 3u, b0, b1);
  kp0 = a0; kp1 = b0; kg0 = a1; kg1 = b1;
#endif

  // initial points: uniform(kp, (1000,2)) * 2 - 1
  const uint32_t bx = random_bits32(kp0, kp1, (uint32_t)(2 * n),     2u * kNP);
  const uint32_t by = random_bits32(kp0, kp1, (uint32_t)(2 * n + 1), 2u * kNP);
  float px = u01(bx) * 2.0f - 1.0f;
  float py = u01(by) * 2.0f - 1.0f;

  for (int i = 0; i < kCI; ++i) {
    // ki = fold_in(kg, i)
    uint32_t ki0, ki1;
    threefry2x32(kg0, kg1, 0u, (uint32_t)i, ki0, ki1);

    float best = -INFINITY;
    int bt = 0;
    #pragma unroll
    for (int t = 0; t < kNT; ++t) {
      const uint32_t bb = random_bits32(ki0, ki1, (uint32_t)(n * kNT + t),
                                        (uint32_t)(kNP * kNT));
      float u = fmaxf(u01(bb), 1.17549435e-38f);     // minval = f32 tiny
      const float g = -logf(-logf(u));               // gumbel
      const float z = dna[t * 7 + 6] + g;            // logits + g
      if (z > best) { best = z; bt = t; }            // first-max like argmax
    }
    const float A = dna[bt * 7 + 0], Bb = dna[bt * 7 + 1];
    const float C = dna[bt * 7 + 2], D  = dna[bt * 7 + 3];
    const float E = dna[bt * 7 + 4], F  = dna[bt * 7 + 5];
    const float nx = A * px + Bb * py + E;
    const float ny = C * px + D  * py + F;
    px = nx; py = ny;
  }

  const float xc = ((px + 1.0f) * 0.5f) * (float)(kW - 1);
  const float yc = ((py + 1.0f) * 0.5f) * (float)(kH - 1);
  int xl = cvt_f32_i32_x86(floorf(xc));
  int yl = cvt_f32_i32_x86(floorf(yc));
  xl = min(max(xl, 0), kW - 2);
  yl = min(max(yl, 0), kH - 2);
  const float xw = xc - (float)xl;   // NOT clipped (matches reference)
  const float yw = yc - (float)yl;

  rec[n] = make_int4(xl, __float_as_int(xw), yl, __float_as_int(yw));
}

// ---------------------------------------------------------------------------
// Kernel 2: per batch row, bilinear gather from x, scatter-add into LDS
// accumulator over H, then out = acc/1000 + bias.
// ---------------------------------------------------------------------------
__global__ __launch_bounds__(256) void fractal_apply(
    const float* __restrict__ x, const float* __restrict__ bias,
    const int4* __restrict__ rec, float* __restrict__ out) {
  __shared__ float acc[kH];
  const int b = blockIdx.x;

  float4* acc4 = reinterpret_cast<float4*>(acc);
  for (int i = threadIdx.x; i < kH / 4; i += 256)
    acc4[i] = make_float4(0.f, 0.f, 0.f, 0.f);
  __syncthreads();

  const float* __restrict__ xrow = x + (size_t)b * kW;
  for (int n = threadIdx.x; n < kNP; n += 256) {
    const int4 r = rec[n];
    const int xl = r.x;
    const float xw = __int_as_float(r.y);
    const int yl = r.z;
    const float yw = __int_as_float(r.w);
    const float xv = xrow[xl] * (1.0f - xw) + xrow[xl + 1] * xw;
    atomicAdd(&acc[yl],     xv * (1.0f - yw));
    atomicAdd(&acc[yl + 1], xv * yw);
  }
  __syncthreads();

  const float4* __restrict__ bias4 = reinterpret_cast<const float4*>(bias);
  float4* __restrict__ out4 = reinterpret_cast<float4*>(out + (size_t)b * kH);
  for (int i = threadIdx.x; i < kH / 4; i += 256) {
    const float4 a  = acc4[i];
    const float4 bi = bias4[i];
    float4 o;
    o.x = a.x / 1000.0f + bi.x;
    o.y = a.y / 1000.0f + bi.y;
    o.z = a.z / 1000.0f + bi.z;
    o.w = a.w / 1000.0f + bi.w;
    out4[i] = o;
  }
}

}  // namespace

extern "C" void kernel_launch(void* const* d_in, const int* in_sizes, int n_in,
                              void* d_out, int out_size, void* d_ws, size_t ws_size,
                              hipStream_t stream) {
  const float* x    = (const float*)d_in[0];   // (2048, 16384)
  const float* dna  = (const float*)d_in[1];   // (56,)
  const float* bias = (const float*)d_in[2];   // (8192,)
  float* out = (float*)d_out;                  // (2048, 8192)
  int4* rec = (int4*)d_ws;                     // 1000 * 16B scratch

  fractal_chaos<<<(kNP + 255) / 256, 256, 0, stream>>>(dna, rec);

  const int B = in_sizes[0] / kW;              // 2048
  fractal_apply<<<B, 256, 0, stream>>>(x, bias, rec, out);
}

// Round 4
// 46.501 us; speedup vs baseline: 1.2502x; 1.2446x over previous
//
#include <hip/hip_runtime.h>
#include <stdint.h>

// ---------------------------------------------------------------------------
// FractalLinear: IFS chaos game (JAX threefry-exact) + bilinear gather/scatter
// ---------------------------------------------------------------------------
#ifndef PRNG_PARTITIONABLE
#define PRNG_PARTITIONABLE 1
#endif

namespace {

constexpr int kH  = 8192;
constexpr int kW  = 16384;
constexpr int kNT = 8;
constexpr int kNP = 1000;
constexpr int kCI = 10;
constexpr int kRPB = 2;          // batch rows per apply-block

__device__ __forceinline__ uint32_t rotl32(uint32_t x, int n) {
  return (x << n) | (x >> (32 - n));
}

// Threefry-2x32, 20 rounds (Random123 / JAX convention).
__device__ void threefry2x32(uint32_t k0, uint32_t k1, uint32_t c0, uint32_t c1,
                             uint32_t& o0, uint32_t& o1) {
  const uint32_t ks2 = k0 ^ k1 ^ 0x1BD11BDAu;
  uint32_t x0 = c0 + k0, x1 = c1 + k1;
#define TF_R(r) { x0 += x1; x1 = rotl32(x1, (r)); x1 ^= x0; }
  TF_R(13) TF_R(15) TF_R(26) TF_R(6)
  x0 += k1;  x1 += ks2 + 1u;
  TF_R(17) TF_R(29) TF_R(16) TF_R(24)
  x0 += ks2; x1 += k0 + 2u;
  TF_R(13) TF_R(15) TF_R(26) TF_R(6)
  x0 += k0;  x1 += k1 + 3u;
  TF_R(17) TF_R(29) TF_R(16) TF_R(24)
  x0 += k1;  x1 += ks2 + 4u;
  TF_R(13) TF_R(15) TF_R(26) TF_R(6)
  x0 += ks2; x1 += k0 + 5u;
#undef TF_R
  o0 = x0; o1 = x1;
}

__device__ __forceinline__ uint32_t random_bits32(uint32_t k0, uint32_t k1,
                                                  uint32_t i, uint32_t size) {
#if PRNG_PARTITIONABLE
  uint32_t o0, o1;
  threefry2x32(k0, k1, 0u /* hi(i) */, i, o0, o1);
  (void)size;
  return o0 ^ o1;
#else
  const uint32_t half = size / 2u;
  const uint32_t j = (i < half) ? i : (i - half);
  uint32_t o0, o1;
  threefry2x32(k0, k1, j, j + half, o0, o1);
  return (i < half) ? o0 : o1;
#endif
}

__device__ __forceinline__ float u01(uint32_t bits) {
  return __uint_as_float((bits >> 9) | 0x3f800000u) - 1.0f;
}

// x86 cvttss2si semantics: out-of-range / NaN -> INT_MIN (matches CPU-ref).
__device__ __forceinline__ int cvt_f32_i32_x86(float v) {
  if (!(v >= -2147483648.0f && v < 2147483648.0f)) return (int)0x80000000;
  return (int)v;
}

// ---------------------------------------------------------------------------
// Kernel 1: chaos game, 8 lanes per point (one transform each).
// All gumbel logits are trajectory-independent -> precompute with full ILP;
// the serial part is only 10x (8-lane argmax-reduce + affine).
// ---------------------------------------------------------------------------
__global__ __launch_bounds__(256) void fractal_chaos(
    const float* __restrict__ dna, int4* __restrict__ rec) {
  const int gid  = blockIdx.x * blockDim.x + threadIdx.x;
  const int n    = gid >> 3;        // point index
  const int lane = gid & 7;         // transform index owned by this lane
  if (n >= kNP) return;             // whole 8-lane group exits together

  // base key = jax.random.key(1) -> (0, 1); kp, kg = split(key, 2)
  uint32_t kp0, kp1, kg0, kg1;
#if PRNG_PARTITIONABLE
  threefry2x32(0u, 1u, 0u, 0u, kp0, kp1);
  threefry2x32(0u, 1u, 0u, 1u, kg0, kg1);
#else
  uint32_t a0, a1, b0, b1;
  threefry2x32(0u, 1u, 0u, 2u, a0, a1);
  threefry2x32(0u, 1u, 1u, 3u, b0, b1);
  kp0 = a0; kp1 = b0; kg0 = a1; kg1 = b1;
#endif

  // this lane's transform parameters (shuffled to the group after argmax)
  const float A  = dna[lane * 7 + 0], Bb = dna[lane * 7 + 1];
  const float C  = dna[lane * 7 + 2], D  = dna[lane * 7 + 3];
  const float E  = dna[lane * 7 + 4], F  = dna[lane * 7 + 5];
  const float P  = dna[lane * 7 + 6];

  // precompute z[i] = logits + gumbel for all iterations (independent of points)
  float z[kCI];
  #pragma unroll
  for (int i = 0; i < kCI; ++i) {
    uint32_t ki0, ki1;
    threefry2x32(kg0, kg1, 0u, (uint32_t)i, ki0, ki1);   // fold_in(kg, i)
    const uint32_t bb = random_bits32(ki0, ki1, (uint32_t)(n * kNT + lane),
                                      (uint32_t)(kNP * kNT));
    const float u = fmaxf(u01(bb), 1.17549435e-38f);
    const float g = -logf(-logf(u));
    z[i] = P + g;
  }

  // initial point: uniform(kp, (1000,2)) * 2 - 1 (computed redundantly per lane)
  const uint32_t bx = random_bits32(kp0, kp1, (uint32_t)(2 * n),     2u * kNP);
  const uint32_t by = random_bits32(kp0, kp1, (uint32_t)(2 * n + 1), 2u * kNP);
  float px = u01(bx) * 2.0f - 1.0f;
  float py = u01(by) * 2.0f - 1.0f;

  #pragma unroll
  for (int i = 0; i < kCI; ++i) {
    // argmax over the 8 lanes, first-index tiebreak (matches jnp.argmax)
    float zb = z[i];
    int   bt = lane;
    #pragma unroll
    for (int m = 1; m < 8; m <<= 1) {
      const float zo = __shfl_xor(zb, m, 8);
      const int   to = __shfl_xor(bt, m, 8);
      if (zo > zb || (zo == zb && to < bt)) { zb = zo; bt = to; }
    }
    const float A_ = __shfl(A,  bt, 8), B_ = __shfl(Bb, bt, 8);
    const float C_ = __shfl(C,  bt, 8), D_ = __shfl(D,  bt, 8);
    const float E_ = __shfl(E,  bt, 8), F_ = __shfl(F,  bt, 8);
    const float nx = A_ * px + B_ * py + E_;
    const float ny = C_ * px + D_ * py + F_;
    px = nx; py = ny;
  }

  if (lane == 0) {
    const float xc = ((px + 1.0f) * 0.5f) * (float)(kW - 1);
    const float yc = ((py + 1.0f) * 0.5f) * (float)(kH - 1);
    int xl = cvt_f32_i32_x86(floorf(xc));
    int yl = cvt_f32_i32_x86(floorf(yc));
    xl = min(max(xl, 0), kW - 2);
    yl = min(max(yl, 0), kH - 2);
    const float xw = xc - (float)xl;   // NOT clipped (matches reference)
    const float yw = yc - (float)yl;
    rec[n] = make_int4(xl, __float_as_int(xw), yl, __float_as_int(yw));
  }
}

// ---------------------------------------------------------------------------
// Kernel 2: 2 batch rows per block, 1024 threads. One gather iteration per
// thread (4 independent loads for ILP), LDS atomic scatter, vector epilogue.
// LDS 64 KiB -> 2 blocks/CU, 32 waves/CU (max occupancy).
// ---------------------------------------------------------------------------
__global__ __launch_bounds__(1024) void fractal_apply(
    const float* __restrict__ x, const float* __restrict__ bias,
    const int4* __restrict__ rec, float* __restrict__ out, int B) {
  __shared__ __align__(16) float acc[kRPB * kH];
  const int b0 = blockIdx.x * kRPB;
  const int nrows = min(kRPB, B - b0);

  float4* acc4 = reinterpret_cast<float4*>(acc);
  constexpr int N4 = kRPB * kH / 4;            // 4096
  for (int i = threadIdx.x; i < N4; i += 1024)
    acc4[i] = make_float4(0.f, 0.f, 0.f, 0.f);
  __syncthreads();

  if (threadIdx.x < kNP) {
    const int4 r = rec[threadIdx.x];
    const int   xl  = r.x;
    const float xw  = __int_as_float(r.y);
    const int   yl  = r.z;
    const float yw  = __int_as_float(r.w);
    const float xw0 = 1.0f - xw;
    const float w0  = 1.0f - yw;
    const float* xp = x + (size_t)b0 * kW + xl;
    #pragma unroll
    for (int rI = 0; rI < kRPB; ++rI) {
      if (rI < nrows) {
        const float xv = xp[(size_t)rI * kW] * xw0 + xp[(size_t)rI * kW + 1] * xw;
        atomicAdd(&acc[rI * kH + yl],     xv * w0);
        atomicAdd(&acc[rI * kH + yl + 1], xv * yw);
      }
    }
  }
  __syncthreads();

  const float4* __restrict__ bias4 = reinterpret_cast<const float4*>(bias);
  for (int i = threadIdx.x; i < N4; i += 1024) {
    const int row = i >> 11;          // i / (kH/4)
    const int col = i & 2047;         // i % (kH/4)
    if (row < nrows) {
      const float4 a  = acc4[i];
      const float4 bi = bias4[col];
      float4 o;
      o.x = a.x / 1000.0f + bi.x;
      o.y = a.y / 1000.0f + bi.y;
      o.z = a.z / 1000.0f + bi.z;
      o.w = a.w / 1000.0f + bi.w;
      reinterpret_cast<float4*>(out + (size_t)(b0 + row) * kH)[col] = o;
    }
  }
}

}  // namespace

extern "C" void kernel_launch(void* const* d_in, const int* in_sizes, int n_in,
                              void* d_out, int out_size, void* d_ws, size_t ws_size,
                              hipStream_t stream) {
  const float* x    = (const float*)d_in[0];   // (2048, 16384)
  const float* dna  = (const float*)d_in[1];   // (56,)
  const float* bias = (const float*)d_in[2];   // (8192,)
  float* out = (float*)d_out;                  // (2048, 8192)
  int4* rec = (int4*)d_ws;                     // 1000 * 16B scratch

  const int chaosThreads = kNP * 8;
  fractal_chaos<<<(chaosThreads + 255) / 256, 256, 0, stream>>>(dna, rec);

  const int B = in_sizes[0] / kW;              // 2048
  fractal_apply<<<(B + kRPB - 1) / kRPB, 1024, 0, stream>>>(x, bias, rec, out, B);
}